// Round 4
// baseline (3932.336 us; speedup 1.0000x reference)
//
#include <hip/hip_runtime.h>
#include <hip/hip_bf16.h>
#include <stdint.h>

typedef __bf16 bf16x8 __attribute__((ext_vector_type(8)));
typedef float  floatx4 __attribute__((ext_vector_type(4)));

static constexpr int kT = 512, kH = 1024, k4H = 4096;

// ---------------------------------------------------------------------------
// Weight pack: wpk[np(256)][c(64)][lane(64)][j(8)] bf16  (MFMA B-fragment order)
// ---------------------------------------------------------------------------
__global__ void pack_w(const float* __restrict__ Wx, const float* __restrict__ Wh,
                       __bf16* __restrict__ wpk) {
  int idx = blockIdx.x * 256 + threadIdx.x;          // 1,048,576 threads
  int l  = idx & 63;
  int c  = (idx >> 6) & 63;
  int np = idx >> 12;                                // 0..255
  int nl = l & 15;
  int g  = nl & 3, hl = nl >> 2;
  int col = g * kH + np * 4 + hl;
  int kf  = (l >> 4) * 8;
  const float* src = (c < 32) ? Wx + (size_t)(c * 32 + kf) * k4H + col
                              : Wh + (size_t)((c - 32) * 32 + kf) * k4H + col;
  bf16x8 v;
#pragma unroll
  for (int j = 0; j < 8; ++j) v[j] = (__bf16)src[(size_t)j * k4H];
  *(bf16x8*)(wpk + (size_t)idx * 8) = v;
}

// ---------------------------------------------------------------------------
// x pack: xpk[t][mt(4)][c(32)][lane(64)][j(8)] bf16  (MFMA A-fragment order)
// ---------------------------------------------------------------------------
__global__ void pack_x(const float* __restrict__ x, __bf16* __restrict__ xpk) {
  int idx = blockIdx.x * 256 + threadIdx.x;          // 4,194,304 threads
  int l  = idx & 63;
  int c  = (idx >> 6) & 31;
  int mt = (idx >> 11) & 3;
  int t  = idx >> 13;
  int m  = mt * 16 + (l & 15);
  int f  = c * 32 + (l >> 4) * 8;
  const float4* src = (const float4*)(x + ((size_t)m * kT + t) * 1024 + f);
  float4 r0 = src[0], r1 = src[1];
  bf16x8 v;
  v[0] = (__bf16)r0.x; v[1] = (__bf16)r0.y; v[2] = (__bf16)r0.z; v[3] = (__bf16)r0.w;
  v[4] = (__bf16)r1.x; v[5] = (__bf16)r1.y; v[6] = (__bf16)r1.z; v[7] = (__bf16)r1.w;
  *(bf16x8*)(xpk + (size_t)idx * 8) = v;
}

// ---------------------------------------------------------------------------
// Persistent scan, 256 WGs x 512 thr (1 WG/CU). WG = (cg 0..63, mq 0..3).
//
// h exchange — EARLY SENTINEL + TAGGED DATA:
//   DATA: hq ring (4 slots), one 8B qword per h-pair: {hi32 = tag = t,
//         lo32 = 2 x bf16}. Stored relaxed/agent by even-ghc gate threads.
//   DETECT: baseline's single dense sentinel line per (mq, cg-quarter),
//         ONE dword per producer WG, polled as ONE 64B line per consumer
//         wave per round (cheapest possible round — R1/R3 lesson).
//   ORDERING: the sentinel needs only ISSUE-ordering after the data
//         stores, provided by LDS flags: each gate wave sets gflag[w]=t
//         after issuing its tagged stores; tid0 spins on the 4 flags
//         (~50cy LDS) and publishes the sentinel BEFORE B3. Sentinel and
//         data visibility race in parallel; B3's vmcnt(0) drain runs
//         concurrently, OFF the inter-WG chain (vs baseline's serial
//         drain -> sentinel = 2 serial fabric hops).
//   BACKSTOP: consumers verify every qword tag == t after the bulk load;
//         stale qwords (sentinel beat data to L3) are retried
//         individually — rare and small, unlike R1/R3 bulk speculation.
//
// Ring margin (3 steps, as baseline): publishing t+4 requires verified
// t+3 data, transitively requires every WG consumed slot t&3. Tags turn
// any violation into a retry, never stale consumption. hq+sent memset
// 0xFF per launch (tag/sentinel 0xFFFFFFFF never matches t < 512).
//
// out store: deferred to the tail (x-waves), so its HBM ack drains at
// B2(t+1) with ~a full x-phase of slack, never on the exchange chain.
//
// hq layout (qwords): [slot(4)][mq(4)][kpair = hcol>>1 (512)][gm(16)]
// ---------------------------------------------------------------------------
__launch_bounds__(512, 2)
__global__ void lstm_scan(const __bf16* __restrict__ xpk, const __bf16* __restrict__ wpk,
                          const float* __restrict__ bias, uint64_t* __restrict__ hq,
                          int* __restrict__ sent, float* __restrict__ out) {
  const int blk  = blockIdx.x;
  const int half = blk & 1;
  const int mq   = (blk >> 1) & 3;
  const int cg   = half * 32 + (blk >> 3);           // 0..63
  const int tid  = threadIdx.x;
  const int wave = tid >> 6;                         // 0..7
  const int lane = tid & 63;

  __shared__ __align__(16) float zbuf[8][16][68];
  __shared__ int gflag[4];                           // per-gate-wave issue flags
  if (tid < 4) gflag[tid] = -1;                      // ordered before use by B2(t=0)

  // ---- persistent weight fragments: breg[ntile][chunk], chunk = wave*8+cc ----
  bf16x8 breg[4][8];
#pragma unroll
  for (int nt = 0; nt < 4; ++nt) {
    const __bf16* wsrc = wpk + (((size_t)(cg * 4 + nt) * 64 + wave * 8) * 64 + lane) * 8;
#pragma unroll
    for (int cc = 0; cc < 8; ++cc)
      breg[nt][cc] = *(const bf16x8*)(wsrc + (size_t)cc * 512);
  }
#pragma unroll
  for (int nt = 0; nt < 4; ++nt)
#pragma unroll
    for (int cc = 0; cc < 8; ++cc)
      asm volatile("" : "+v"(breg[nt][cc]));         // pin: no remat from memory

  // ---- gate-phase per-thread state (threads 0..255) ----
  const int gm   = (tid >> 4) & 15;
  const int ghc  = tid & 15;
  const int m_g  = mq * 16 + gm;
  const int hcol = cg * 16 + ghc;
  const int gnt  = ghc >> 2, ghl = ghc & 3;
  float c_state  = 0.f;
  float h_keep   = 0.f;                              // out-store deferred to tail
  const float bi = bias[0 * kH + hcol], bf_ = bias[1 * kH + hcol];
  const float bg = bias[2 * kH + hcol], bo  = bias[3 * kH + hcol];
  // tagged-qword index within a slot: (mq*512 + hcol/2)*16 + gm
  const int qoff = ((mq * 512 + cg * 8 + (ghc >> 1)) * 16) + gm;

  floatx4 acc[4];
#pragma unroll
  for (int nt = 0; nt < 4; ++nt) acc[nt] = floatx4{0.f, 0.f, 0.f, 0.f};

  // ---- prologue: x-part of t=0 (h_{-1}=0 so h-waves contribute zero) ----
  if (wave < 4) {
    const __bf16* asrc = xpk + ((size_t)mq * 32 + wave * 8) * 512 + (size_t)lane * 8;
#pragma unroll
    for (int cc = 0; cc < 8; ++cc) {
      bf16x8 a = *(const bf16x8*)(asrc + (size_t)cc * 512);
#pragma unroll
      for (int nt = 0; nt < 4; ++nt)
        acc[nt] = __builtin_amdgcn_mfma_f32_16x16x32_bf16(a, breg[nt][cc], acc[nt], 0, 0, 0);
    }
  }

#pragma unroll 1
  for (int t = 0; t < kT; ++t) {
    // publish partials to LDS (all zbuf readers of step t-1 passed B3 already)
#pragma unroll
    for (int nt = 0; nt < 4; ++nt)
#pragma unroll
      for (int rr = 0; rr < 4; ++rr)
        zbuf[wave][(lane >> 4) * 4 + rr][nt * 16 + (lane & 15)] = acc[nt][rr];
    __syncthreads();                                 // B2: zbuf complete

    if (tid < 256) {
      float zi = bi, zf = bf_, zg = bg, zo = bo;
      const float* zp = &zbuf[0][gm][gnt * 16 + ghl * 4];
#pragma unroll
      for (int w = 0; w < 8; ++w) {
        floatx4 zv = *(const floatx4*)(zp + (size_t)w * 16 * 68);
        zi += zv[0]; zf += zv[1]; zg += zv[2]; zo += zv[3];
      }
      float ig = 1.f / (1.f + __expf(-zi));
      float fg = 1.f / (1.f + __expf(-zf));
      float gg = 2.f / (1.f + __expf(-2.f * zg)) - 1.f;
      float og = 1.f / (1.f + __expf(-zo));
      c_state = fg * c_state + ig * gg;
      float tc = 2.f / (1.f + __expf(-2.f * c_state)) - 1.f;
      float h  = og * tc;
      h_keep = h;
      // --- tagged publish (critical path) ---
      __bf16 hb16 = (__bf16)h;
      uint16_t hbits;
      __builtin_memcpy(&hbits, &hb16, 2);
      uint32_t mine = hbits;
      uint32_t partner = (uint32_t)__shfl_xor((int)mine, 1);   // ghc^1, same wave
      if ((ghc & 1) == 0) {
        uint64_t qw = ((uint64_t)(uint32_t)t << 32)
                    | (uint64_t)(mine | (partner << 16));
        __hip_atomic_store(&hq[(size_t)(t & 3) * 32768 + qoff], qw,
                           __ATOMIC_RELAXED, __HIP_MEMORY_SCOPE_AGENT);
      }
      // issue-fence: this wave's tagged stores precede its flag
      asm volatile("" ::: "memory");
      if (lane == 0)
        __hip_atomic_store(&gflag[wave], t, __ATOMIC_RELAXED,
                           __HIP_MEMORY_SCOPE_WORKGROUP);
      // tid0: wait all 4 gate waves ISSUED (LDS, ~50cy), publish sentinel
      // BEFORE B3 — sentinel visibility races in parallel with data drain.
      if (tid == 0) {
        for (;;) {
          int a = __hip_atomic_load(&gflag[1], __ATOMIC_RELAXED, __HIP_MEMORY_SCOPE_WORKGROUP);
          int b = __hip_atomic_load(&gflag[2], __ATOMIC_RELAXED, __HIP_MEMORY_SCOPE_WORKGROUP);
          int c = __hip_atomic_load(&gflag[3], __ATOMIC_RELAXED, __HIP_MEMORY_SCOPE_WORKGROUP);
          if (a == t && b == t && c == t) break;
        }
        asm volatile("" ::: "memory");
        __hip_atomic_store(&sent[(((t & 7) * 4 + mq) * 4 + (cg >> 4)) * 16 + (cg & 15)], t,
                           __ATOMIC_RELAXED, __HIP_MEMORY_SCOPE_AGENT);
      }
    }
    __syncthreads();                                 // B3: zbuf reuse protection

    // ---- tail ----
    // deferred out-store (every t, incl. t=511): x-wave slack absorbs ack
    if (wave < 4)
      __builtin_nontemporal_store(h_keep, &out[((size_t)m_g * kT + t) * kH + hcol]);

    if (t < kT - 1) {
#pragma unroll
      for (int nt = 0; nt < 4; ++nt) acc[nt] = floatx4{0.f, 0.f, 0.f, 0.f};
      if (wave < 4) {                                // x-part of t+1: runs ahead
        const __bf16* asrc = xpk + (((size_t)(t + 1) * 4 + mq) * 32 + wave * 8) * 512
                           + (size_t)lane * 8;
#pragma unroll
        for (int cc = 0; cc < 8; ++cc) {
          bf16x8 a = __builtin_nontemporal_load((const bf16x8*)(asrc + (size_t)cc * 512));
#pragma unroll
          for (int nt = 0; nt < 4; ++nt)
            acc[nt] = __builtin_amdgcn_mfma_f32_16x16x32_bf16(a, breg[nt][cc], acc[nt], 0, 0, 0);
        }
      } else {                                       // h-part: cheap poll, tagged load
        const int s = wave - 4;
        const int* sline = sent + (((t & 7) * 4 + mq) * 4 + s) * 16 + (lane & 15);
        int guard = 0;
        for (;;) {
          int v = __hip_atomic_load(sline, __ATOMIC_RELAXED, __HIP_MEMORY_SCOPE_AGENT);
          if (__all(v == t)) break;                  // all 16 producers published
          __builtin_amdgcn_s_sleep(2);
          if (++guard > (1 << 20)) break;            // fail loud, not hung
        }
        asm volatile("" ::: "memory");               // no hoisting data loads above poll
        const uint64_t* hb = hq + (size_t)(t & 3) * 32768 + (size_t)mq * 8192
                           + (size_t)s * 2048 + (size_t)(lane >> 4) * 64 + (size_t)(lane & 15);
        uint64_t w[8][4];
#pragma unroll
        for (int c = 0; c < 8; ++c)
#pragma unroll
          for (int d = 0; d < 4; ++d)
            w[c][d] = __hip_atomic_load(hb + (size_t)c * 256 + d * 16,
                                        __ATOMIC_RELAXED, __HIP_MEMORY_SCOPE_AGENT);
        // verify tags; retry ONLY stale qwords (rare: sentinel/data skew)
        const uint64_t pat = (uint64_t)(uint32_t)t << 32;
        const uint64_t msk = 0xFFFFFFFF00000000ull;
        int guard2 = 0;
        for (;;) {
          uint64_t bad = 0;
#pragma unroll
          for (int c = 0; c < 8; ++c)
#pragma unroll
            for (int d = 0; d < 4; ++d)
              bad |= (w[c][d] ^ pat) & msk;
          if (__all(bad == 0)) break;
          __builtin_amdgcn_s_sleep(1);
#pragma unroll
          for (int c = 0; c < 8; ++c)
#pragma unroll
            for (int d = 0; d < 4; ++d)
              if ((w[c][d] ^ pat) & msk)
                w[c][d] = __hip_atomic_load(hb + (size_t)c * 256 + d * 16,
                                            __ATOMIC_RELAXED, __HIP_MEMORY_SCOPE_AGENT);
          if (++guard2 > (1 << 20)) break;           // fail loud, not hung
        }
        asm volatile("" ::: "memory");
#pragma unroll
        for (int c = 0; c < 8; ++c) {
          union { uint32_t d[4]; bf16x8 v; } u;
#pragma unroll
          for (int d0 = 0; d0 < 4; ++d0) u.d[d0] = (uint32_t)w[c][d0];
#pragma unroll
          for (int nt = 0; nt < 4; ++nt)
            acc[nt] = __builtin_amdgcn_mfma_f32_16x16x32_bf16(u.v, breg[nt][c], acc[nt], 0, 0, 0);
        }
      }
    }
  }
}

// ---------------------------------------------------------------------------
extern "C" void kernel_launch(void* const* d_in, const int* in_sizes, int n_in,
                              void* d_out, int out_size, void* d_ws, size_t ws_size,
                              hipStream_t stream) {
  const float* x  = (const float*)d_in[0];   // [64,512,1024]
  const float* Wx = (const float*)d_in[1];   // [1024,4096]
  const float* Wh = (const float*)d_in[2];   // [1024,4096]
  const float* b  = (const float*)d_in[3];   // [4096]
  float* out = (float*)d_out;

  char* ws = (char*)d_ws;
  int*      snt = (int*)ws;                                 // 8 KB sentinel lines
  uint64_t* hqb = (uint64_t*)(ws + ((size_t)1 << 16));      // 1 MB tagged-h ring
  __bf16*   wpk = (__bf16*)(ws + ((size_t)0x110000));       // 16 MB
  __bf16*   xpk = (__bf16*)(ws + ((size_t)0x1110000));      // 64 MB (total ~81 MB)
  (void)in_sizes; (void)n_in; (void)out_size; (void)ws_size;

  // poison sentinels + tags: 0xFFFFFFFF never equals a valid t < 512
  hipMemsetAsync(ws, 0xFF, (size_t)0x110000, stream);

  hipLaunchKernelGGL(pack_w, dim3(4096),  dim3(256), 0, stream, Wx, Wh, wpk);
  hipLaunchKernelGGL(pack_x, dim3(16384), dim3(256), 0, stream, x, xpk);
  hipLaunchKernelGGL(lstm_scan, dim3(256), dim3(512), 0, stream,
                     xpk, wpk, b, hqb, snt, out);
}

// Round 5
// 1894.509 us; speedup vs baseline: 2.0756x; 2.0756x over previous
//
#include <hip/hip_runtime.h>
#include <hip/hip_bf16.h>
#include <stdint.h>

typedef __bf16 bf16x8 __attribute__((ext_vector_type(8)));
typedef float  floatx4 __attribute__((ext_vector_type(4)));

static constexpr int kT = 512, kH = 1024, k4H = 4096;

// ---------------------------------------------------------------------------
// Weight pack: wpk[np(256)][c(64)][lane(64)][j(8)] bf16  (MFMA B-fragment order)
//   n_local = lane&15 = hl*4 + g  (gates interleaved inside each 16-wide n-tile)
//   col_W   = g*1024 + np*4 + hl ;  np = cg*4 + nt  ->  hcol = cg*16 + nt*4 + hl
//   fused k = c*32 + (lane>>4)*8 + j   (c<32: Wx rows, c>=32: Wh rows)
// ---------------------------------------------------------------------------
__global__ void pack_w(const float* __restrict__ Wx, const float* __restrict__ Wh,
                       __bf16* __restrict__ wpk) {
  int idx = blockIdx.x * 256 + threadIdx.x;          // 1,048,576 threads
  int l  = idx & 63;
  int c  = (idx >> 6) & 63;
  int np = idx >> 12;                                // 0..255
  int nl = l & 15;
  int g  = nl & 3, hl = nl >> 2;
  int col = g * kH + np * 4 + hl;
  int kf  = (l >> 4) * 8;
  const float* src = (c < 32) ? Wx + (size_t)(c * 32 + kf) * k4H + col
                              : Wh + (size_t)((c - 32) * 32 + kf) * k4H + col;
  bf16x8 v;
#pragma unroll
  for (int j = 0; j < 8; ++j) v[j] = (__bf16)src[(size_t)j * k4H];
  *(bf16x8*)(wpk + (size_t)idx * 8) = v;
}

// ---------------------------------------------------------------------------
// x pack: xpk[t][mt(4)][c(32)][lane(64)][j(8)] bf16  (MFMA A-fragment order)
//   m = mt*16 + (lane&15),  k = c*32 + (lane>>4)*8 + j
// ---------------------------------------------------------------------------
__global__ void pack_x(const float* __restrict__ x, __bf16* __restrict__ xpk) {
  int idx = blockIdx.x * 256 + threadIdx.x;          // 4,194,304 threads
  int l  = idx & 63;
  int c  = (idx >> 6) & 31;
  int mt = (idx >> 11) & 3;
  int t  = idx >> 13;
  int m  = mt * 16 + (l & 15);
  int f  = c * 32 + (l >> 4) * 8;
  const float4* src = (const float4*)(x + ((size_t)m * kT + t) * 1024 + f);
  float4 r0 = src[0], r1 = src[1];
  bf16x8 v;
  v[0] = (__bf16)r0.x; v[1] = (__bf16)r0.y; v[2] = (__bf16)r0.z; v[3] = (__bf16)r0.w;
  v[4] = (__bf16)r1.x; v[5] = (__bf16)r1.y; v[6] = (__bf16)r1.z; v[7] = (__bf16)r1.w;
  *(bf16x8*)(xpk + (size_t)idx * 8) = v;
}

// ---------------------------------------------------------------------------
// Persistent scan, 256 WGs x 512 thr (1 WG/CU). WG = (cg 0..63, mq 0..3).
// EXACT round-0 baseline protocol (drain-then-sentinel; proven fastest over
// 4 protocol-variant rounds), with ONE mechanism change:
//   OUT-STORE OFF THE B3 DRAIN. Baseline issued a NONTEMPORAL out store in
//   the gate phase; B3's __syncthreads drains vmcnt(0), so every step's
//   exchange waited on an HBM-side NT write ack (~1.2-2k cy) instead of just
//   the L3 ack of the h-stores (~700 cy). Now: plain (L2-ack, write-back)
//   store, issued in the TAIL by waves 0-3 before their x-loads — its ack
//   folds into B2(t+1) where x-waves have ~2k cy slack and are never the
//   stragglers. Everything else byte-identical to round 0.
//
// h exchange, two structures:
//   DATA: hd ring (4 slots), packed 2xbf16/dword, written sc1 by gate threads,
//         read ONCE per step by consumers (16 dwordx2 sc1 loads, no retry).
//   DETECT: per-producer sentinel dwords, 16 per 64B line = one line per
//         (mq, slice). Producer writes sent[..][cg&15] = t AFTER B3 (barrier's
//         vmcnt(0) drain orders it after the h stores). Consumer polls ONE
//         line per iteration + s_sleep throttle -> no fabric storm.
// No atomically-RMW'd flags anywhere; sentinel value==t is poison/init-safe
// (ring mod 8). Data-ring overwrite margin: 3 steps (proof: publishing t+4
// requires sentinels t+3, which requires every WG consumed slot t&3).
// hd layout (dwords): [slot(4)][mq(4)][hg=hcol>>3 (128)][gm(16)][d=(hcol&7)/2 (4)]
// ---------------------------------------------------------------------------
__launch_bounds__(512, 2)
__global__ void lstm_scan(const __bf16* __restrict__ xpk, const __bf16* __restrict__ wpk,
                          const float* __restrict__ bias, uint32_t* __restrict__ hd,
                          int* __restrict__ sent, float* __restrict__ out) {
  const int blk  = blockIdx.x;
  const int half = blk & 1;
  const int mq   = (blk >> 1) & 3;
  const int cg   = half * 32 + (blk >> 3);           // 0..63
  const int tid  = threadIdx.x;
  const int wave = tid >> 6;                         // 0..7
  const int lane = tid & 63;

  __shared__ __align__(16) float zbuf[8][16][68];

  // ---- persistent weight fragments: breg[ntile][chunk], chunk = wave*8+cc ----
  bf16x8 breg[4][8];
#pragma unroll
  for (int nt = 0; nt < 4; ++nt) {
    const __bf16* wsrc = wpk + (((size_t)(cg * 4 + nt) * 64 + wave * 8) * 64 + lane) * 8;
#pragma unroll
    for (int cc = 0; cc < 8; ++cc)
      breg[nt][cc] = *(const bf16x8*)(wsrc + (size_t)cc * 512);
  }
#pragma unroll
  for (int nt = 0; nt < 4; ++nt)
#pragma unroll
    for (int cc = 0; cc < 8; ++cc)
      asm volatile("" : "+v"(breg[nt][cc]));         // pin: no remat from memory

  // ---- gate-phase per-thread state (threads 0..255) ----
  const int gm   = (tid >> 4) & 15;
  const int ghc  = tid & 15;
  const int m_g  = mq * 16 + gm;
  const int hcol = cg * 16 + ghc;
  const int gnt  = ghc >> 2, ghl = ghc & 3;
  float c_state  = 0.f;
  float h_keep   = 0.f;                              // out-store deferred to tail
  const float bi = bias[0 * kH + hcol], bf_ = bias[1 * kH + hcol];
  const float bg = bias[2 * kH + hcol], bo  = bias[3 * kH + hcol];
  // packed-h dword index (minus slot term slot*32768)
  const int hdoff = ((mq * 128 + cg * 2 + (ghc >> 3)) * 16 + gm) * 4 + ((ghc & 7) >> 1);

  floatx4 acc[4];
#pragma unroll
  for (int nt = 0; nt < 4; ++nt) acc[nt] = floatx4{0.f, 0.f, 0.f, 0.f};

  // ---- prologue: x-part of t=0 (h_{-1}=0 so h-waves contribute zero) ----
  if (wave < 4) {
    const __bf16* asrc = xpk + ((size_t)mq * 32 + wave * 8) * 512 + (size_t)lane * 8;
#pragma unroll
    for (int cc = 0; cc < 8; ++cc) {
      bf16x8 a = *(const bf16x8*)(asrc + (size_t)cc * 512);
#pragma unroll
      for (int nt = 0; nt < 4; ++nt)
        acc[nt] = __builtin_amdgcn_mfma_f32_16x16x32_bf16(a, breg[nt][cc], acc[nt], 0, 0, 0);
    }
  }

#pragma unroll 1
  for (int t = 0; t < kT; ++t) {
    // publish partials to LDS (all zbuf readers of step t-1 passed B3 already)
#pragma unroll
    for (int nt = 0; nt < 4; ++nt)
#pragma unroll
      for (int rr = 0; rr < 4; ++rr)
        zbuf[wave][(lane >> 4) * 4 + rr][nt * 16 + (lane & 15)] = acc[nt][rr];
    __syncthreads();                                 // B2: zbuf complete

    if (tid < 256) {
      float zi = bi, zf = bf_, zg = bg, zo = bo;
      const float* zp = &zbuf[0][gm][gnt * 16 + ghl * 4];
#pragma unroll
      for (int w = 0; w < 8; ++w) {
        floatx4 zv = *(const floatx4*)(zp + (size_t)w * 16 * 68);
        zi += zv[0]; zf += zv[1]; zg += zv[2]; zo += zv[3];
      }
      float ig = 1.f / (1.f + __expf(-zi));
      float fg = 1.f / (1.f + __expf(-zf));
      float gg = 2.f / (1.f + __expf(-2.f * zg)) - 1.f;
      float og = 1.f / (1.f + __expf(-zo));
      c_state = fg * c_state + ig * gg;
      float tc = 2.f / (1.f + __expf(-2.f * c_state)) - 1.f;
      float h  = og * tc;
      h_keep = h;                                    // out-store moved to tail
      // publish packed h (critical path) — the ONLY vmem store B3 now drains
      __bf16 hb16 = (__bf16)h;
      uint16_t hbits;
      __builtin_memcpy(&hbits, &hb16, 2);
      uint32_t mine = hbits;
      uint32_t partner = (uint32_t)__shfl_xor((int)mine, 1);   // ghc^1, same wave
      if ((ghc & 1) == 0) {
        uint32_t packed = mine | (partner << 16);
        __hip_atomic_store(&hd[(size_t)(t & 3) * 32768 + hdoff], packed,
                           __ATOMIC_RELAXED, __HIP_MEMORY_SCOPE_AGENT);
      }
    }
    __syncthreads();                                 // B3: vmcnt(0) drain -> h at coherence pt

    // sentinel publish: this WG's 16 h-cols for step t are globally visible
    if (tid == 0)
      __hip_atomic_store(&sent[(((t & 7) * 4 + mq) * 4 + (cg >> 4)) * 16 + (cg & 15)], t,
                         __ATOMIC_RELAXED, __HIP_MEMORY_SCOPE_AGENT);

    // deferred out-store: plain (L2-ack) store, every t incl. the last; its
    // write-back to HBM proceeds off the exchange chain and its ack drains
    // at B2(t+1) where x-waves have slack.
    if (wave < 4)
      out[((size_t)m_g * kT + t) * kH + hcol] = h_keep;

    // ---- tail: partials for step t+1 ----
    if (t < kT - 1) {
#pragma unroll
      for (int nt = 0; nt < 4; ++nt) acc[nt] = floatx4{0.f, 0.f, 0.f, 0.f};
      if (wave < 4) {                                // x-part of t+1: runs ahead
        const __bf16* asrc = xpk + (((size_t)(t + 1) * 4 + mq) * 32 + wave * 8) * 512
                           + (size_t)lane * 8;
#pragma unroll
        for (int cc = 0; cc < 8; ++cc) {
          bf16x8 a = __builtin_nontemporal_load((const bf16x8*)(asrc + (size_t)cc * 512));
#pragma unroll
          for (int nt = 0; nt < 4; ++nt)
            acc[nt] = __builtin_amdgcn_mfma_f32_16x16x32_bf16(a, breg[nt][cc], acc[nt], 0, 0, 0);
        }
      } else {                                       // h-part: light poll, one-shot load
        const int s = wave - 4;
        const int* sline = sent + (((t & 7) * 4 + mq) * 4 + s) * 16 + (lane & 15);
        int guard = 0;
        for (;;) {
          int v = __hip_atomic_load(sline, __ATOMIC_RELAXED, __HIP_MEMORY_SCOPE_AGENT);
          if (__all(v == t)) break;                  // all 16 producers published
          __builtin_amdgcn_s_sleep(2);
          if (++guard > (1 << 20)) break;            // fail loud, not hung
        }
        asm volatile("" ::: "memory");               // no hoisting data loads above poll
        const uint64_t* hb = (const uint64_t*)hd + (size_t)(t & 3) * 16384
                           + ((size_t)(mq * 128 + s * 32 + (lane >> 4)) * 16 + (lane & 15)) * 2;
        uint64_t w[8][2];
#pragma unroll
        for (int c = 0; c < 8; ++c) {
          w[c][0] = __hip_atomic_load(hb + (size_t)c * 128,     __ATOMIC_RELAXED,
                                      __HIP_MEMORY_SCOPE_AGENT);
          w[c][1] = __hip_atomic_load(hb + (size_t)c * 128 + 1, __ATOMIC_RELAXED,
                                      __HIP_MEMORY_SCOPE_AGENT);
        }
#pragma unroll
        for (int c = 0; c < 8; ++c) {
          union { uint64_t q[2]; bf16x8 v; } u;
          u.q[0] = w[c][0]; u.q[1] = w[c][1];
#pragma unroll
          for (int nt = 0; nt < 4; ++nt)
            acc[nt] = __builtin_amdgcn_mfma_f32_16x16x32_bf16(u.v, breg[nt][c], acc[nt], 0, 0, 0);
        }
      }
    }
  }
}

// ---------------------------------------------------------------------------
extern "C" void kernel_launch(void* const* d_in, const int* in_sizes, int n_in,
                              void* d_out, int out_size, void* d_ws, size_t ws_size,
                              hipStream_t stream) {
  const float* x  = (const float*)d_in[0];   // [64,512,1024]
  const float* Wx = (const float*)d_in[1];   // [1024,4096]
  const float* Wh = (const float*)d_in[2];   // [1024,4096]
  const float* b  = (const float*)d_in[3];   // [4096]
  float* out = (float*)d_out;

  char* ws = (char*)d_ws;
  int*      snt = (int*)ws;                                 // 8 KB sentinel lines
  uint32_t* hdb = (uint32_t*)(ws + ((size_t)1 << 16));      // 512 KB packed-h ring
  __bf16*   wpk = (__bf16*)(ws + ((size_t)1 << 20));        // 16 MB
  __bf16*   xpk = (__bf16*)(ws + ((size_t)17 << 20));       // 64 MB  (total 81 MB)
  (void)in_sizes; (void)n_in; (void)out_size; (void)ws_size;

  hipLaunchKernelGGL(pack_w, dim3(4096),  dim3(256), 0, stream, Wx, Wh, wpk);
  hipLaunchKernelGGL(pack_x, dim3(16384), dim3(256), 0, stream, x, xpk);
  hipLaunchKernelGGL(lstm_scan, dim3(256), dim3(512), 0, stream,
                     xpk, wpk, b, hdb, snt, out);
}

// Round 6
// 1745.721 us; speedup vs baseline: 2.2526x; 1.0852x over previous
//
#include <hip/hip_runtime.h>
#include <hip/hip_bf16.h>
#include <stdint.h>

typedef __bf16 bf16x8 __attribute__((ext_vector_type(8)));
typedef float  floatx4 __attribute__((ext_vector_type(4)));
typedef unsigned int uint32x4 __attribute__((ext_vector_type(4)));

static constexpr int kT = 512, kH = 1024, k4H = 4096;

// ---------------------------------------------------------------------------
// Weight pack: wpk[np(256)][c(64)][lane(64)][j(8)] bf16  (MFMA B-fragment order)
//   n_local = lane&15 = hl*4 + g  (gates interleaved inside each 16-wide n-tile)
//   col_W   = g*1024 + np*4 + hl ;  np = cg*4 + nt  ->  hcol = cg*16 + nt*4 + hl
//   fused k = c*32 + (lane>>4)*8 + j   (c<32: Wx rows, c>=32: Wh rows)
// ---------------------------------------------------------------------------
__global__ void pack_w(const float* __restrict__ Wx, const float* __restrict__ Wh,
                       __bf16* __restrict__ wpk) {
  int idx = blockIdx.x * 256 + threadIdx.x;          // 1,048,576 threads
  int l  = idx & 63;
  int c  = (idx >> 6) & 63;
  int np = idx >> 12;                                // 0..255
  int nl = l & 15;
  int g  = nl & 3, hl = nl >> 2;
  int col = g * kH + np * 4 + hl;
  int kf  = (l >> 4) * 8;
  const float* src = (c < 32) ? Wx + (size_t)(c * 32 + kf) * k4H + col
                              : Wh + (size_t)((c - 32) * 32 + kf) * k4H + col;
  bf16x8 v;
#pragma unroll
  for (int j = 0; j < 8; ++j) v[j] = (__bf16)src[(size_t)j * k4H];
  *(bf16x8*)(wpk + (size_t)idx * 8) = v;
}

// ---------------------------------------------------------------------------
// x pack: xpk[t][mt(4)][c(32)][lane(64)][j(8)] bf16  (MFMA A-fragment order)
//   m = mt*16 + (lane&15),  k = c*32 + (lane>>4)*8 + j
// ---------------------------------------------------------------------------
__global__ void pack_x(const float* __restrict__ x, __bf16* __restrict__ xpk) {
  int idx = blockIdx.x * 256 + threadIdx.x;          // 4,194,304 threads
  int l  = idx & 63;
  int c  = (idx >> 6) & 31;
  int mt = (idx >> 11) & 3;
  int t  = idx >> 13;
  int m  = mt * 16 + (l & 15);
  int f  = c * 32 + (l >> 4) * 8;
  const float4* src = (const float4*)(x + ((size_t)m * kT + t) * 1024 + f);
  float4 r0 = src[0], r1 = src[1];
  bf16x8 v;
  v[0] = (__bf16)r0.x; v[1] = (__bf16)r0.y; v[2] = (__bf16)r0.z; v[3] = (__bf16)r0.w;
  v[4] = (__bf16)r1.x; v[5] = (__bf16)r1.y; v[6] = (__bf16)r1.z; v[7] = (__bf16)r1.w;
  *(bf16x8*)(xpk + (size_t)idx * 8) = v;
}

// ---------------------------------------------------------------------------
// Persistent scan, 256 WGs x 512 thr (1 WG/CU). WG = (cg 0..63, mq 0..3).
// Protocol: R5 baseline (drain-then-sentinel; proven best over 5 rounds).
//
// BIGRING=1 (if ws_size permits): NO-REUSE h ring, 512 regions x 128 KB,
//   region = bitrev9(t) (non-monotonic -> defeats stream prefetch).
//   Because a region's addresses are touched exactly once, and only AFTER
//   its sentinel is seen, consumer-XCD L2s can never hold stale lines for
//   them -> consumers use PLAIN CACHED loads. The 64 WGs of one mq land on
//   XCDs {2mq, 2mq+1} (round-robin dispatch), so ~32 WGs/XCD dedup their
//   identical 32 KB h reads through the XCD L2: MALL read traffic per step
//   drops 8 MB -> ~256 KB, and most data-load hops become ~200cy L2 hits.
//   Producer stores remain agent-scope bypass (land in MALL = the
//   rendezvous); drain-then-sentinel ordering unchanged.
// BIGRING=0: exact R5 kernel (4-slot ring + bypass loads) as fallback.
//
// hd layout (dwords): [region][mq(4)][hg=hcol>>3 (128)][gm(16)][d=(hcol&7)/2 (4)]
// ---------------------------------------------------------------------------
template<int BIGRING>
__launch_bounds__(512, 2)
__global__ void lstm_scan(const __bf16* __restrict__ xpk, const __bf16* __restrict__ wpk,
                          const float* __restrict__ bias, uint32_t* __restrict__ hd,
                          int* __restrict__ sent, float* __restrict__ out) {
  const int blk  = blockIdx.x;
  const int half = blk & 1;
  const int mq   = (blk >> 1) & 3;
  const int cg   = half * 32 + (blk >> 3);           // 0..63
  const int tid  = threadIdx.x;
  const int wave = tid >> 6;                         // 0..7
  const int lane = tid & 63;

  __shared__ __align__(16) float zbuf[8][16][68];

  // ---- persistent weight fragments: breg[ntile][chunk], chunk = wave*8+cc ----
  bf16x8 breg[4][8];
#pragma unroll
  for (int nt = 0; nt < 4; ++nt) {
    const __bf16* wsrc = wpk + (((size_t)(cg * 4 + nt) * 64 + wave * 8) * 64 + lane) * 8;
#pragma unroll
    for (int cc = 0; cc < 8; ++cc)
      breg[nt][cc] = *(const bf16x8*)(wsrc + (size_t)cc * 512);
  }
#pragma unroll
  for (int nt = 0; nt < 4; ++nt)
#pragma unroll
    for (int cc = 0; cc < 8; ++cc)
      asm volatile("" : "+v"(breg[nt][cc]));         // pin: no remat from memory

  // ---- gate-phase per-thread state (threads 0..255) ----
  const int gm   = (tid >> 4) & 15;
  const int ghc  = tid & 15;
  const int m_g  = mq * 16 + gm;
  const int hcol = cg * 16 + ghc;
  const int gnt  = ghc >> 2, ghl = ghc & 3;
  float c_state  = 0.f;
  float h_keep   = 0.f;                              // out-store deferred to tail
  const float bi = bias[0 * kH + hcol], bf_ = bias[1 * kH + hcol];
  const float bg = bias[2 * kH + hcol], bo  = bias[3 * kH + hcol];
  // packed-h dword index (minus region term region*32768)
  const int hdoff = ((mq * 128 + cg * 2 + (ghc >> 3)) * 16 + gm) * 4 + ((ghc & 7) >> 1);

  floatx4 acc[4];
#pragma unroll
  for (int nt = 0; nt < 4; ++nt) acc[nt] = floatx4{0.f, 0.f, 0.f, 0.f};

  // ---- prologue: x-part of t=0 (h_{-1}=0 so h-waves contribute zero) ----
  if (wave < 4) {
    const __bf16* asrc = xpk + ((size_t)mq * 32 + wave * 8) * 512 + (size_t)lane * 8;
#pragma unroll
    for (int cc = 0; cc < 8; ++cc) {
      bf16x8 a = *(const bf16x8*)(asrc + (size_t)cc * 512);
#pragma unroll
      for (int nt = 0; nt < 4; ++nt)
        acc[nt] = __builtin_amdgcn_mfma_f32_16x16x32_bf16(a, breg[nt][cc], acc[nt], 0, 0, 0);
    }
  }

#pragma unroll 1
  for (int t = 0; t < kT; ++t) {
    // region index: no-reuse bit-reversed (BIGRING) or 4-slot ring (fallback)
    const int region = BIGRING ? (int)(__brev((unsigned)t) >> 23) : (t & 3);

    // publish partials to LDS (all zbuf readers of step t-1 passed B3 already)
#pragma unroll
    for (int nt = 0; nt < 4; ++nt)
#pragma unroll
      for (int rr = 0; rr < 4; ++rr)
        zbuf[wave][(lane >> 4) * 4 + rr][nt * 16 + (lane & 15)] = acc[nt][rr];
    __syncthreads();                                 // B2: zbuf complete

    if (tid < 256) {
      float zi = bi, zf = bf_, zg = bg, zo = bo;
      const float* zp = &zbuf[0][gm][gnt * 16 + ghl * 4];
#pragma unroll
      for (int w = 0; w < 8; ++w) {
        floatx4 zv = *(const floatx4*)(zp + (size_t)w * 16 * 68);
        zi += zv[0]; zf += zv[1]; zg += zv[2]; zo += zv[3];
      }
      float ig = 1.f / (1.f + __expf(-zi));
      float fg = 1.f / (1.f + __expf(-zf));
      float gg = 2.f / (1.f + __expf(-2.f * zg)) - 1.f;
      float og = 1.f / (1.f + __expf(-zo));
      c_state = fg * c_state + ig * gg;
      float tc = 2.f / (1.f + __expf(-2.f * c_state)) - 1.f;
      float h  = og * tc;
      h_keep = h;                                    // out-store moved to tail
      // publish packed h (critical path) — the ONLY vmem store B3 drains
      __bf16 hb16 = (__bf16)h;
      uint16_t hbits;
      __builtin_memcpy(&hbits, &hb16, 2);
      uint32_t mine = hbits;
      uint32_t partner = (uint32_t)__shfl_xor((int)mine, 1);   // ghc^1, same wave
      if ((ghc & 1) == 0) {
        uint32_t packed = mine | (partner << 16);
        __hip_atomic_store(&hd[(size_t)region * 32768 + hdoff], packed,
                           __ATOMIC_RELAXED, __HIP_MEMORY_SCOPE_AGENT);
      }
    }
    __syncthreads();                                 // B3: vmcnt(0) drain -> h at coherence pt

    // sentinel publish: this WG's 16 h-cols for step t are globally visible
    if (tid == 0)
      __hip_atomic_store(&sent[(((t & 7) * 4 + mq) * 4 + (cg >> 4)) * 16 + (cg & 15)], t,
                         __ATOMIC_RELAXED, __HIP_MEMORY_SCOPE_AGENT);

    // deferred out-store: plain (L2-ack) store; write-back off the chain
    if (wave < 4)
      out[((size_t)m_g * kT + t) * kH + hcol] = h_keep;

    // ---- tail: partials for step t+1 ----
    if (t < kT - 1) {
#pragma unroll
      for (int nt = 0; nt < 4; ++nt) acc[nt] = floatx4{0.f, 0.f, 0.f, 0.f};
      if (wave < 4) {                                // x-part of t+1: runs ahead
        const __bf16* asrc = xpk + (((size_t)(t + 1) * 4 + mq) * 32 + wave * 8) * 512
                           + (size_t)lane * 8;
#pragma unroll
        for (int cc = 0; cc < 8; ++cc) {
          bf16x8 a = __builtin_nontemporal_load((const bf16x8*)(asrc + (size_t)cc * 512));
#pragma unroll
          for (int nt = 0; nt < 4; ++nt)
            acc[nt] = __builtin_amdgcn_mfma_f32_16x16x32_bf16(a, breg[nt][cc], acc[nt], 0, 0, 0);
        }
      } else {                                       // h-part: light poll, one-shot load
        const int s = wave - 4;
        const int* sline = sent + (((t & 7) * 4 + mq) * 4 + s) * 16 + (lane & 15);
        int guard = 0;
        for (;;) {
          int v = __hip_atomic_load(sline, __ATOMIC_RELAXED, __HIP_MEMORY_SCOPE_AGENT);
          if (__all(v == t)) break;                  // all 16 producers published
          __builtin_amdgcn_s_sleep(2);
          if (++guard > (1 << 20)) break;            // fail loud, not hung
        }
        asm volatile("" ::: "memory");               // no hoisting data loads above poll
        const uint64_t* hb = (const uint64_t*)hd + (size_t)region * 16384
                           + ((size_t)(mq * 128 + s * 32 + (lane >> 4)) * 16 + (lane & 15)) * 2;
        uint64_t w[8][2];
        if (BIGRING) {
          // plain cached 16B loads: fresh addresses -> no stale-L2 risk;
          // XCD L2 dedups the ~32 co-located readers of identical bytes
#pragma unroll
          for (int c = 0; c < 8; ++c) {
            uint32x4 ld = *(const uint32x4*)(hb + (size_t)c * 128);
            w[c][0] = (uint64_t)ld.x | ((uint64_t)ld.y << 32);
            w[c][1] = (uint64_t)ld.z | ((uint64_t)ld.w << 32);
          }
        } else {
#pragma unroll
          for (int c = 0; c < 8; ++c) {
            w[c][0] = __hip_atomic_load(hb + (size_t)c * 128,     __ATOMIC_RELAXED,
                                        __HIP_MEMORY_SCOPE_AGENT);
            w[c][1] = __hip_atomic_load(hb + (size_t)c * 128 + 1, __ATOMIC_RELAXED,
                                        __HIP_MEMORY_SCOPE_AGENT);
          }
        }
#pragma unroll
        for (int c = 0; c < 8; ++c) {
          union { uint64_t q[2]; bf16x8 v; } u;
          u.q[0] = w[c][0]; u.q[1] = w[c][1];
#pragma unroll
          for (int nt = 0; nt < 4; ++nt)
            acc[nt] = __builtin_amdgcn_mfma_f32_16x16x32_bf16(u.v, breg[nt][c], acc[nt], 0, 0, 0);
        }
      }
    }
  }
}

// ---------------------------------------------------------------------------
extern "C" void kernel_launch(void* const* d_in, const int* in_sizes, int n_in,
                              void* d_out, int out_size, void* d_ws, size_t ws_size,
                              hipStream_t stream) {
  const float* x  = (const float*)d_in[0];   // [64,512,1024]
  const float* Wx = (const float*)d_in[1];   // [1024,4096]
  const float* Wh = (const float*)d_in[2];   // [1024,4096]
  const float* b  = (const float*)d_in[3];   // [4096]
  float* out = (float*)d_out;
  (void)in_sizes; (void)n_in; (void)out_size;

  char* ws = (char*)d_ws;
  // BIGRING layout: sent@0 (64KB) | ring@0x10000 (64MB) | wpk (16MB) | xpk (64MB)
  const size_t big_need = (size_t)0x10000 + ((size_t)64 << 20) + ((size_t)16 << 20)
                        + ((size_t)64 << 20);        // ~144.1 MB

  if (ws_size >= big_need) {
    int*      snt = (int*)ws;
    uint32_t* hdb = (uint32_t*)(ws + (size_t)0x10000);
    __bf16*   wpk = (__bf16*)(ws + (size_t)0x10000 + ((size_t)64 << 20));
    __bf16*   xpk = (__bf16*)(ws + (size_t)0x10000 + ((size_t)80 << 20));
    hipLaunchKernelGGL(pack_w, dim3(4096),  dim3(256), 0, stream, Wx, Wh, wpk);
    hipLaunchKernelGGL(pack_x, dim3(16384), dim3(256), 0, stream, x, xpk);
    hipLaunchKernelGGL(lstm_scan<1>, dim3(256), dim3(512), 0, stream,
                       xpk, wpk, b, hdb, snt, out);
  } else {
    // exact R5 fallback layout: sent@0 | ring@64KB (512KB) | wpk@1MB | xpk@17MB
    int*      snt = (int*)ws;
    uint32_t* hdb = (uint32_t*)(ws + ((size_t)1 << 16));
    __bf16*   wpk = (__bf16*)(ws + ((size_t)1 << 20));
    __bf16*   xpk = (__bf16*)(ws + ((size_t)17 << 20));
    hipLaunchKernelGGL(pack_w, dim3(4096),  dim3(256), 0, stream, Wx, Wh, wpk);
    hipLaunchKernelGGL(pack_x, dim3(16384), dim3(256), 0, stream, x, xpk);
    hipLaunchKernelGGL(lstm_scan<0>, dim3(256), dim3(512), 0, stream,
                       xpk, wpk, b, hdb, snt, out);
  }
}

// Round 8
// 1711.269 us; speedup vs baseline: 2.2979x; 1.0201x over previous
//
#include <hip/hip_runtime.h>
#include <hip/hip_bf16.h>
#include <stdint.h>

typedef __bf16 bf16x8 __attribute__((ext_vector_type(8)));
typedef float  floatx4 __attribute__((ext_vector_type(4)));
typedef unsigned int uint32x4 __attribute__((ext_vector_type(4)));

static constexpr int kT = 512, kH = 1024, k4H = 4096;

// ---------------------------------------------------------------------------
// Weight pack: wpk[np(256)][c(64)][lane(64)][j(8)] bf16  (MFMA B-fragment order)
//   n_local = lane&15 = hl*4 + g  (gates interleaved inside each 16-wide n-tile)
//   col_W   = g*1024 + np*4 + hl ;  np = cg*4 + nt  ->  hcol = cg*16 + nt*4 + hl
//   fused k = c*32 + (lane>>4)*8 + j   (c<32: Wx rows, c>=32: Wh rows)
// ---------------------------------------------------------------------------
__global__ void pack_w(const float* __restrict__ Wx, const float* __restrict__ Wh,
                       __bf16* __restrict__ wpk) {
  int idx = blockIdx.x * 256 + threadIdx.x;          // 1,048,576 threads
  int l  = idx & 63;
  int c  = (idx >> 6) & 63;
  int np = idx >> 12;                                // 0..255
  int nl = l & 15;
  int g  = nl & 3, hl = nl >> 2;
  int col = g * kH + np * 4 + hl;
  int kf  = (l >> 4) * 8;
  const float* src = (c < 32) ? Wx + (size_t)(c * 32 + kf) * k4H + col
                              : Wh + (size_t)((c - 32) * 32 + kf) * k4H + col;
  bf16x8 v;
#pragma unroll
  for (int j = 0; j < 8; ++j) v[j] = (__bf16)src[(size_t)j * k4H];
  *(bf16x8*)(wpk + (size_t)idx * 8) = v;
}

// ---------------------------------------------------------------------------
// x pack: xpk[t][mt(4)][c(32)][lane(64)][j(8)] bf16  (MFMA A-fragment order)
//   m = mt*16 + (lane&15),  k = c*32 + (lane>>4)*8 + j
// ---------------------------------------------------------------------------
__global__ void pack_x(const float* __restrict__ x, __bf16* __restrict__ xpk) {
  int idx = blockIdx.x * 256 + threadIdx.x;          // 4,194,304 threads
  int l  = idx & 63;
  int c  = (idx >> 6) & 31;
  int mt = (idx >> 11) & 3;
  int t  = idx >> 13;
  int m  = mt * 16 + (l & 15);
  int f  = c * 32 + (l >> 4) * 8;
  const float4* src = (const float4*)(x + ((size_t)m * kT + t) * 1024 + f);
  float4 r0 = src[0], r1 = src[1];
  bf16x8 v;
  v[0] = (__bf16)r0.x; v[1] = (__bf16)r0.y; v[2] = (__bf16)r0.z; v[3] = (__bf16)r0.w;
  v[4] = (__bf16)r1.x; v[5] = (__bf16)r1.y; v[6] = (__bf16)r1.z; v[7] = (__bf16)r1.w;
  *(bf16x8*)(xpk + (size_t)idx * 8) = v;
}

// ---------------------------------------------------------------------------
// Persistent scan, 256 WGs x 512 thr (1 WG/CU). WG = (cg 0..63, mq 0..3).
// Protocol: R6 winner (drain-then-sentinel + BIGRING no-reuse h ring with
// plain-cached consumer loads), with ONE change:
//   X TAIL LOADS ARE PLAIN CACHED (was __builtin_nontemporal_load / slc).
//   NT loads bypass L2 retention, so the 64 WGs of each mq re-read the SAME
//   32 KB x-slice from the MALL every step (~8 MB/step, ~4 GB/kernel of
//   redundant MALL reads — invisible in FETCH_SIZE because xpk is L3-
//   resident). That traffic queues the fabric that the exchange's drain /
//   sentinel / poll / h-first-touch must cross. Plain loads let the XCD L2
//   dedup: first toucher pays MALL, ~31 WGs hit L2; MALL x traffic drops
//   ~125x. xpk is read-only, written by a prior dispatch -> cached loads
//   are correct (prologue already uses plain loads).
//
// BIGRING=1: NO-REUSE h ring, 512 regions x 128 KB, region = bitrev9(t).
//   Consumers use plain cached loads (fresh addresses, never stale; loads
//   ordered after the sentinel poll). Producers store agent-scope to MALL.
// BIGRING=0: R5 fallback (4-slot ring + bypass loads) if ws too small.
//
// hd layout (dwords): [region][mq(4)][hg=hcol>>3 (128)][gm(16)][d=(hcol&7)/2 (4)]
// ---------------------------------------------------------------------------
template<int BIGRING>
__launch_bounds__(512, 2)
__global__ void lstm_scan(const __bf16* __restrict__ xpk, const __bf16* __restrict__ wpk,
                          const float* __restrict__ bias, uint32_t* __restrict__ hd,
                          int* __restrict__ sent, float* __restrict__ out) {
  const int blk  = blockIdx.x;
  const int half = blk & 1;
  const int mq   = (blk >> 1) & 3;
  const int cg   = half * 32 + (blk >> 3);           // 0..63
  const int tid  = threadIdx.x;
  const int wave = tid >> 6;                         // 0..7
  const int lane = tid & 63;

  __shared__ __align__(16) float zbuf[8][16][68];

  // ---- persistent weight fragments: breg[ntile][chunk], chunk = wave*8+cc ----
  bf16x8 breg[4][8];
#pragma unroll
  for (int nt = 0; nt < 4; ++nt) {
    const __bf16* wsrc = wpk + (((size_t)(cg * 4 + nt) * 64 + wave * 8) * 64 + lane) * 8;
#pragma unroll
    for (int cc = 0; cc < 8; ++cc)
      breg[nt][cc] = *(const bf16x8*)(wsrc + (size_t)cc * 512);
  }
#pragma unroll
  for (int nt = 0; nt < 4; ++nt)
#pragma unroll
    for (int cc = 0; cc < 8; ++cc)
      asm volatile("" : "+v"(breg[nt][cc]));         // pin: no remat from memory

  // ---- gate-phase per-thread state (threads 0..255) ----
  const int gm   = (tid >> 4) & 15;
  const int ghc  = tid & 15;
  const int m_g  = mq * 16 + gm;
  const int hcol = cg * 16 + ghc;
  const int gnt  = ghc >> 2, ghl = ghc & 3;
  float c_state  = 0.f;
  float h_keep   = 0.f;                              // out-store deferred to tail
  const float bi = bias[0 * kH + hcol], bf_ = bias[1 * kH + hcol];
  const float bg = bias[2 * kH + hcol], bo  = bias[3 * kH + hcol];
  // packed-h dword index (minus region term region*32768)
  const int hdoff = ((mq * 128 + cg * 2 + (ghc >> 3)) * 16 + gm) * 4 + ((ghc & 7) >> 1);

  floatx4 acc[4];
#pragma unroll
  for (int nt = 0; nt < 4; ++nt) acc[nt] = floatx4{0.f, 0.f, 0.f, 0.f};

  // ---- prologue: x-part of t=0 (h_{-1}=0 so h-waves contribute zero) ----
  if (wave < 4) {
    const __bf16* asrc = xpk + ((size_t)mq * 32 + wave * 8) * 512 + (size_t)lane * 8;
#pragma unroll
    for (int cc = 0; cc < 8; ++cc) {
      bf16x8 a = *(const bf16x8*)(asrc + (size_t)cc * 512);
#pragma unroll
      for (int nt = 0; nt < 4; ++nt)
        acc[nt] = __builtin_amdgcn_mfma_f32_16x16x32_bf16(a, breg[nt][cc], acc[nt], 0, 0, 0);
    }
  }

#pragma unroll 1
  for (int t = 0; t < kT; ++t) {
    // region index: no-reuse bit-reversed (BIGRING) or 4-slot ring (fallback)
    const int region = BIGRING ? (int)(__brev((unsigned)t) >> 23) : (t & 3);

    // publish partials to LDS (all zbuf readers of step t-1 passed B3 already)
#pragma unroll
    for (int nt = 0; nt < 4; ++nt)
#pragma unroll
      for (int rr = 0; rr < 4; ++rr)
        zbuf[wave][(lane >> 4) * 4 + rr][nt * 16 + (lane & 15)] = acc[nt][rr];
    __syncthreads();                                 // B2: zbuf complete

    if (tid < 256) {
      float zi = bi, zf = bf_, zg = bg, zo = bo;
      const float* zp = &zbuf[0][gm][gnt * 16 + ghl * 4];
#pragma unroll
      for (int w = 0; w < 8; ++w) {
        floatx4 zv = *(const floatx4*)(zp + (size_t)w * 16 * 68);
        zi += zv[0]; zf += zv[1]; zg += zv[2]; zo += zv[3];
      }
      float ig = 1.f / (1.f + __expf(-zi));
      float fg = 1.f / (1.f + __expf(-zf));
      float gg = 2.f / (1.f + __expf(-2.f * zg)) - 1.f;
      float og = 1.f / (1.f + __expf(-zo));
      c_state = fg * c_state + ig * gg;
      float tc = 2.f / (1.f + __expf(-2.f * c_state)) - 1.f;
      float h  = og * tc;
      h_keep = h;                                    // out-store moved to tail
      // publish packed h (critical path) — the ONLY vmem store B3 drains
      __bf16 hb16 = (__bf16)h;
      uint16_t hbits;
      __builtin_memcpy(&hbits, &hb16, 2);
      uint32_t mine = hbits;
      uint32_t partner = (uint32_t)__shfl_xor((int)mine, 1);   // ghc^1, same wave
      if ((ghc & 1) == 0) {
        uint32_t packed = mine | (partner << 16);
        __hip_atomic_store(&hd[(size_t)region * 32768 + hdoff], packed,
                           __ATOMIC_RELAXED, __HIP_MEMORY_SCOPE_AGENT);
      }
    }
    __syncthreads();                                 // B3: vmcnt(0) drain -> h at coherence pt

    // sentinel publish: this WG's 16 h-cols for step t are globally visible
    if (tid == 0)
      __hip_atomic_store(&sent[(((t & 7) * 4 + mq) * 4 + (cg >> 4)) * 16 + (cg & 15)], t,
                         __ATOMIC_RELAXED, __HIP_MEMORY_SCOPE_AGENT);

    // deferred out-store: plain (L2-ack) store; write-back off the chain
    if (wave < 4)
      out[((size_t)m_g * kT + t) * kH + hcol] = h_keep;

    // ---- tail: partials for step t+1 ----
    if (t < kT - 1) {
#pragma unroll
      for (int nt = 0; nt < 4; ++nt) acc[nt] = floatx4{0.f, 0.f, 0.f, 0.f};
      if (wave < 4) {                                // x-part of t+1: runs ahead
        const __bf16* asrc = xpk + (((size_t)(t + 1) * 4 + mq) * 32 + wave * 8) * 512
                           + (size_t)lane * 8;
#pragma unroll
        for (int cc = 0; cc < 8; ++cc) {
          // PLAIN cached load (was nontemporal): XCD L2 dedups the ~32
          // co-located WGs reading the same x-slice -> MALL decongestion
          bf16x8 a = *(const bf16x8*)(asrc + (size_t)cc * 512);
#pragma unroll
          for (int nt = 0; nt < 4; ++nt)
            acc[nt] = __builtin_amdgcn_mfma_f32_16x16x32_bf16(a, breg[nt][cc], acc[nt], 0, 0, 0);
        }
      } else {                                       // h-part: light poll, one-shot load
        const int s = wave - 4;
        const int* sline = sent + (((t & 7) * 4 + mq) * 4 + s) * 16 + (lane & 15);
        int guard = 0;
        for (;;) {
          int v = __hip_atomic_load(sline, __ATOMIC_RELAXED, __HIP_MEMORY_SCOPE_AGENT);
          if (__all(v == t)) break;                  // all 16 producers published
          __builtin_amdgcn_s_sleep(2);
          if (++guard > (1 << 20)) break;            // fail loud, not hung
        }
        asm volatile("" ::: "memory");               // no hoisting data loads above poll
        const uint64_t* hb = (const uint64_t*)hd + (size_t)region * 16384
                           + ((size_t)(mq * 128 + s * 32 + (lane >> 4)) * 16 + (lane & 15)) * 2;
        uint64_t w[8][2];
        if (BIGRING) {
          // plain cached 16B loads: fresh addresses -> no stale-L2 risk;
          // XCD L2 dedups the ~32 co-located readers of identical bytes
#pragma unroll
          for (int c = 0; c < 8; ++c) {
            uint32x4 ld = *(const uint32x4*)(hb + (size_t)c * 128);
            w[c][0] = (uint64_t)ld.x | ((uint64_t)ld.y << 32);
            w[c][1] = (uint64_t)ld.z | ((uint64_t)ld.w << 32);
          }
        } else {
#pragma unroll
          for (int c = 0; c < 8; ++c) {
            w[c][0] = __hip_atomic_load(hb + (size_t)c * 128,     __ATOMIC_RELAXED,
                                        __HIP_MEMORY_SCOPE_AGENT);
            w[c][1] = __hip_atomic_load(hb + (size_t)c * 128 + 1, __ATOMIC_RELAXED,
                                        __HIP_MEMORY_SCOPE_AGENT);
          }
        }
#pragma unroll
        for (int c = 0; c < 8; ++c) {
          union { uint64_t q[2]; bf16x8 v; } u;
          u.q[0] = w[c][0]; u.q[1] = w[c][1];
#pragma unroll
          for (int nt = 0; nt < 4; ++nt)
            acc[nt] = __builtin_amdgcn_mfma_f32_16x16x32_bf16(u.v, breg[nt][c], acc[nt], 0, 0, 0);
        }
      }
    }
  }
}

// ---------------------------------------------------------------------------
extern "C" void kernel_launch(void* const* d_in, const int* in_sizes, int n_in,
                              void* d_out, int out_size, void* d_ws, size_t ws_size,
                              hipStream_t stream) {
  const float* x  = (const float*)d_in[0];   // [64,512,1024]
  const float* Wx = (const float*)d_in[1];   // [1024,4096]
  const float* Wh = (const float*)d_in[2];   // [1024,4096]
  const float* b  = (const float*)d_in[3];   // [4096]
  float* out = (float*)d_out;
  (void)in_sizes; (void)n_in; (void)out_size;

  char* ws = (char*)d_ws;
  // BIGRING layout: sent@0 (64KB) | ring@0x10000 (64MB) | wpk (16MB) | xpk (64MB)
  const size_t big_need = (size_t)0x10000 + ((size_t)64 << 20) + ((size_t)16 << 20)
                        + ((size_t)64 << 20);        // ~144.1 MB

  if (ws_size >= big_need) {
    int*      snt = (int*)ws;
    uint32_t* hdb = (uint32_t*)(ws + (size_t)0x10000);
    __bf16*   wpk = (__bf16*)(ws + (size_t)0x10000 + ((size_t)64 << 20));
    __bf16*   xpk = (__bf16*)(ws + (size_t)0x10000 + ((size_t)80 << 20));
    hipLaunchKernelGGL(pack_w, dim3(4096),  dim3(256), 0, stream, Wx, Wh, wpk);
    hipLaunchKernelGGL(pack_x, dim3(16384), dim3(256), 0, stream, x, xpk);
    hipLaunchKernelGGL(lstm_scan<1>, dim3(256), dim3(512), 0, stream,
                       xpk, wpk, b, hdb, snt, out);
  } else {
    // R5 fallback layout: sent@0 | ring@64KB (512KB) | wpk@1MB | xpk@17MB
    int*      snt = (int*)ws;
    uint32_t* hdb = (uint32_t*)(ws + ((size_t)1 << 16));
    __bf16*   wpk = (__bf16*)(ws + ((size_t)1 << 20));
    __bf16*   xpk = (__bf16*)(ws + ((size_t)17 << 20));
    hipLaunchKernelGGL(pack_w, dim3(4096),  dim3(256), 0, stream, Wx, Wh, wpk);
    hipLaunchKernelGGL(pack_x, dim3(16384), dim3(256), 0, stream, x, xpk);
    hipLaunchKernelGGL(lstm_scan<0>, dim3(256), dim3(512), 0, stream,
                       xpk, wpk, b, hdb, snt, out);
  }
}